// Round 10
// baseline (330.148 us; speedup 1.0000x reference)
//
#include <hip/hip_runtime.h>
#include <hip/hip_bf16.h>

#define N_NODES 50000
#define N_EDGES 800000
#define D_IN 128
#define D_H 64
#define SCAN_BLOCKS 196   // ceil(50000/256)
#define HIST_BLOCKS 3125  // N_EDGES/256
#define LIN1_BLOCKS 782   // ceil(3125 waves / 4)

// W-fragment table offsets (in ushorts): [kt][nt][lane][8] per matrix
#define F1L 0
#define F1R 8192
#define F2L 16384
#define F2R 20480
#define F3L 24576
#define F3R 28672
#define FRAG_TOTAL 32768  // 64 KB

#define PLANE ((size_t)N_NODES * 32)   // one feature-half plane, in ushorts

typedef short bf16x8 __attribute__((ext_vector_type(8)));
typedef float f32x4 __attribute__((ext_vector_type(4)));

__device__ __forceinline__ ushort f2bf(float f) {
    __hip_bfloat16 b = __float2bfloat16(f);
    return *reinterpret_cast<ushort*>(&b);
}
__device__ __forceinline__ float bf16_lo(unsigned int u) { return __uint_as_float(u << 16); }
__device__ __forceinline__ float bf16_hi(unsigned int u) { return __uint_as_float(u & 0xffff0000u); }

// ---------- W-fragment build (device helper) ----------
__device__ __forceinline__ void build_frag_one(const float* __restrict__ W, int local,
                                               ushort* __restrict__ frag, int fid) {
    int lane = local & 63;
    int ktnt = local >> 6;
    int kt = ktnt >> 2, nt = ktnt & 3;
    int quad = lane >> 4, col = lane & 15;
    ushort t0 = f2bf(W[(kt * 32 + quad * 8 + 0) * D_H + nt * 16 + col]);
    ushort t1 = f2bf(W[(kt * 32 + quad * 8 + 1) * D_H + nt * 16 + col]);
    ushort t2 = f2bf(W[(kt * 32 + quad * 8 + 2) * D_H + nt * 16 + col]);
    ushort t3 = f2bf(W[(kt * 32 + quad * 8 + 3) * D_H + nt * 16 + col]);
    ushort t4 = f2bf(W[(kt * 32 + quad * 8 + 4) * D_H + nt * 16 + col]);
    ushort t5 = f2bf(W[(kt * 32 + quad * 8 + 5) * D_H + nt * 16 + col]);
    ushort t6 = f2bf(W[(kt * 32 + quad * 8 + 6) * D_H + nt * 16 + col]);
    ushort t7 = f2bf(W[(kt * 32 + quad * 8 + 7) * D_H + nt * 16 + col]);
    uint4 v;
    v.x = (unsigned int)t0 | ((unsigned int)t1 << 16);
    v.y = (unsigned int)t2 | ((unsigned int)t3 << 16);
    v.z = (unsigned int)t4 | ((unsigned int)t5 << 16);
    v.w = (unsigned int)t6 | ((unsigned int)t7 << 16);
    *reinterpret_cast<uint4*>(frag + (size_t)fid * 8) = v;
}

// ---------- K1: hist+rank (3125 blocks) || build_frags (16 blocks) ----------
__global__ void hist_frags_kernel(const int* __restrict__ dstv, int* __restrict__ cnt,
                                  ushort* __restrict__ rank,
                                  const float* __restrict__ Wl1, const float* __restrict__ Wr1,
                                  const float* __restrict__ Wl2, const float* __restrict__ Wr2,
                                  const float* __restrict__ Wl3, const float* __restrict__ Wr3,
                                  ushort* __restrict__ frag) {
    if (blockIdx.x < HIST_BLOCKS) {
        int e = blockIdx.x * 256 + threadIdx.x;
        if (e < N_EDGES) {
            int r = atomicAdd(&cnt[dstv[e]], 1);
            rank[e] = (ushort)r;
        }
    } else {
        int fid = (blockIdx.x - HIST_BLOCKS) * 256 + threadIdx.x;  // 0..4095
        const float* W; int base;
        if (fid < 1024)      { W = Wl1; base = 0; }
        else if (fid < 2048) { W = Wr1; base = 1024; }
        else if (fid < 2560) { W = Wl2; base = 2048; }
        else if (fid < 3072) { W = Wr2; base = 2560; }
        else if (fid < 3584) { W = Wl3; base = 3072; }
        else                 { W = Wr3; base = 3584; }
        build_frag_one(W, fid - base, frag, fid);
    }
}

// ---------- K2: per-block partial sums ----------
__global__ void scan_partial(const int* __restrict__ cnt, int* __restrict__ blockSums) {
    __shared__ int s[256];
    int i = blockIdx.x * 256 + threadIdx.x;
    s[threadIdx.x] = (i < N_NODES) ? cnt[i] : 0;
    __syncthreads();
    for (int off = 128; off > 0; off >>= 1) {
        if (threadIdx.x < off) s[threadIdx.x] += s[threadIdx.x + off];
        __syncthreads();
    }
    if (threadIdx.x == 0) blockSums[blockIdx.x] = s[0];
}

// ---------- K3: fused blockSums-scan + final scan ----------
__global__ void scan_final(const int* __restrict__ cnt, const int* __restrict__ blockSums,
                           int* __restrict__ row_ptr) {
    __shared__ int s[256];
    __shared__ int bs[256];
    int t = threadIdx.x;
    bs[t] = (t < SCAN_BLOCKS) ? blockSums[t] : 0;
    int i = blockIdx.x * 256 + t;
    s[t] = (i < N_NODES) ? cnt[i] : 0;
    __syncthreads();
    for (int off = 1; off < 256; off <<= 1) {
        int tmp1 = (t >= off) ? s[t - off] : 0;
        int tmp2 = (t >= off) ? bs[t - off] : 0;
        __syncthreads();
        s[t] += tmp1;
        bs[t] += tmp2;
        __syncthreads();
    }
    int blockExcl = (blockIdx.x > 0) ? bs[blockIdx.x - 1] : 0;
    int excl = blockExcl + ((t > 0) ? s[t - 1] : 0);
    if (i < N_NODES) row_ptr[i] = excl;
    if (i == 0) row_ptr[N_NODES] = N_EDGES;
}

// ---------- lin bodies: Ylo/Yhi = bf16(h@Wl) planes, Zb = bf16(h@Wr) ----------
// A-frag: lane holds h[m0+(lane&15)][kt*32+(lane>>4)*8+j]; D: row=quad*4+reg, col nt*16+(lane&15)
__device__ __forceinline__ void lin_store(int m0, int quad, int col,
                                          f32x4 accl0, f32x4 accl1, f32x4 accl2, f32x4 accl3,
                                          f32x4 accr0, f32x4 accr1, f32x4 accr2, f32x4 accr3,
                                          ushort* __restrict__ Ylo, ushort* __restrict__ Yhi,
                                          ushort* __restrict__ Zb) {
#pragma unroll
    for (int reg = 0; reg < 4; ++reg) {
        size_t row = (size_t)(m0 + quad * 4 + reg);
        ushort* ylo = Ylo + row * 32;
        ushort* yhi = Yhi + row * 32;
        ylo[col]      = f2bf(accl0[reg]);
        ylo[16 + col] = f2bf(accl1[reg]);
        yhi[col]      = f2bf(accl2[reg]);
        yhi[16 + col] = f2bf(accl3[reg]);
        ushort* zp = Zb + row * D_H;
        zp[0 * 16 + col] = f2bf(accr0[reg]);
        zp[1 * 16 + col] = f2bf(accr1[reg]);
        zp[2 * 16 + col] = f2bf(accr2[reg]);
        zp[3 * 16 + col] = f2bf(accr3[reg]);
    }
}

#define LOAD_FRAGS(KT, fragWl, fragWr)                                                     \
    bf16x8 blf[KT][4], brf[KT][4];                                                         \
    _Pragma("unroll") for (int kt = 0; kt < KT; ++kt)                                      \
        _Pragma("unroll") for (int nt = 0; nt < 4; ++nt) {                                 \
            size_t off = (size_t)((kt * 4 + nt) * 64 + lane) * 8;                          \
            blf[kt][nt] = __builtin_bit_cast(bf16x8, *reinterpret_cast<const uint4*>(fragWl + off)); \
            brf[kt][nt] = __builtin_bit_cast(bf16x8, *reinterpret_cast<const uint4*>(fragWr + off)); \
        }

#define MFMA8(a, kt)                                                                 \
    accl0 = __builtin_amdgcn_mfma_f32_16x16x32_bf16(a, blf[kt][0], accl0, 0, 0, 0);  \
    accl1 = __builtin_amdgcn_mfma_f32_16x16x32_bf16(a, blf[kt][1], accl1, 0, 0, 0);  \
    accl2 = __builtin_amdgcn_mfma_f32_16x16x32_bf16(a, blf[kt][2], accl2, 0, 0, 0);  \
    accl3 = __builtin_amdgcn_mfma_f32_16x16x32_bf16(a, blf[kt][3], accl3, 0, 0, 0);  \
    accr0 = __builtin_amdgcn_mfma_f32_16x16x32_bf16(a, brf[kt][0], accr0, 0, 0, 0);  \
    accr1 = __builtin_amdgcn_mfma_f32_16x16x32_bf16(a, brf[kt][1], accr1, 0, 0, 0);  \
    accr2 = __builtin_amdgcn_mfma_f32_16x16x32_bf16(a, brf[kt][2], accr2, 0, 0, 0);  \
    accr3 = __builtin_amdgcn_mfma_f32_16x16x32_bf16(a, brf[kt][3], accr3, 0, 0, 0);

// ---------- K4: layer-1 linYZ (fp32 x in, 782 blocks) || rank-based CSR fill ----------
__global__ void lin1_fill_kernel(const float* __restrict__ x, const ushort* __restrict__ wfrag,
                                 const int* __restrict__ srcv, const int* __restrict__ dstv,
                                 const ushort* __restrict__ rank, const int* __restrict__ row_ptr,
                                 ushort* __restrict__ csr_src,
                                 ushort* __restrict__ Ylo, ushort* __restrict__ Yhi,
                                 ushort* __restrict__ Zb) {
    if (blockIdx.x < LIN1_BLOCKS) {
        int gwave = (blockIdx.x * 256 + threadIdx.x) >> 6;
        int lane = threadIdx.x & 63;
        int m0 = gwave * 16;
        if (m0 >= N_NODES) return;
        int col = lane & 15, quad = lane >> 4;
        LOAD_FRAGS(4, (wfrag + F1L), (wfrag + F1R))
        f32x4 accl0 = {0.f,0.f,0.f,0.f}, accl1 = accl0, accl2 = accl0, accl3 = accl0;
        f32x4 accr0 = accl0, accr1 = accl0, accr2 = accl0, accr3 = accl0;
        const float* arow = x + (size_t)(m0 + col) * D_IN + quad * 8;
#pragma unroll
        for (int kt = 0; kt < 4; ++kt) {
            float4 a_lo = *reinterpret_cast<const float4*>(arow + kt * 32);
            float4 a_hi = *reinterpret_cast<const float4*>(arow + kt * 32 + 4);
            bf16x8 a;
            a[0] = (short)f2bf(a_lo.x); a[1] = (short)f2bf(a_lo.y);
            a[2] = (short)f2bf(a_lo.z); a[3] = (short)f2bf(a_lo.w);
            a[4] = (short)f2bf(a_hi.x); a[5] = (short)f2bf(a_hi.y);
            a[6] = (short)f2bf(a_hi.z); a[7] = (short)f2bf(a_hi.w);
            MFMA8(a, kt)
        }
        lin_store(m0, quad, col, accl0, accl1, accl2, accl3, accr0, accr1, accr2, accr3,
                  Ylo, Yhi, Zb);
    } else {
        int e = (blockIdx.x - LIN1_BLOCKS) * 256 + threadIdx.x;
        if (e < N_EDGES) {
            int d = dstv[e];
            int pos = row_ptr[d] + (int)rank[e];
            csr_src[pos] = (ushort)srcv[e];
        }
    }
}

// ---------- layers 2/3 linYZ (bf16 plane input) ----------
__global__ void linYZ_b_kernel(const ushort* __restrict__ Hlo, const ushort* __restrict__ Hhi,
                               const ushort* __restrict__ fragWl, const ushort* __restrict__ fragWr,
                               ushort* __restrict__ Ylo, ushort* __restrict__ Yhi,
                               ushort* __restrict__ Zb) {
    int gwave = (blockIdx.x * 256 + threadIdx.x) >> 6;
    int lane = threadIdx.x & 63;
    int m0 = gwave * 16;
    if (m0 >= N_NODES) return;
    int col = lane & 15, quad = lane >> 4;
    LOAD_FRAGS(2, fragWl, fragWr)
    f32x4 accl0 = {0.f,0.f,0.f,0.f}, accl1 = accl0, accl2 = accl0, accl3 = accl0;
    f32x4 accr0 = accl0, accr1 = accl0, accr2 = accl0, accr3 = accl0;
    {
        const ushort* arow = Hlo + (size_t)(m0 + col) * 32 + quad * 8;
        bf16x8 a = __builtin_bit_cast(bf16x8, *reinterpret_cast<const uint4*>(arow));
        MFMA8(a, 0)
    }
    {
        const ushort* arow = Hhi + (size_t)(m0 + col) * 32 + quad * 8;
        bf16x8 a = __builtin_bit_cast(bf16x8, *reinterpret_cast<const uint4*>(arow));
        MFMA8(a, 1)
    }
    lin_store(m0, quad, col, accl0, accl1, accl2, accl3, accr0, accr1, accr2, accr3,
              Ylo, Yhi, Zb);
}

// ---------- per-node gather over two L2-resident feature-half planes ----------
// wave = 1 node; 8 groups of 8 lanes; group g handles edge k+8t+g; lane-chunk l (0..7)
// covers 4 features of the 64-B half-row (one load instr = 8 rows in flight).
template <bool FUSE_PROJ>
__global__ void gather_kernel(const ushort* __restrict__ Ylo, const ushort* __restrict__ Yhi,
                              const ushort* __restrict__ Zb, const float* __restrict__ bl,
                              const int* __restrict__ row_ptr, const ushort* __restrict__ csr_src,
                              ushort* __restrict__ Olo, ushort* __restrict__ Ohi,
                              const float* __restrict__ Wp,
                              float* __restrict__ ps, float* __restrict__ pd) {
    int node = (blockIdx.x << 2) + (threadIdx.x >> 6);
    int lane = threadIdx.x & 63;
    if (node >= N_NODES) return;
    int g = lane >> 3;   // 0..7
    int l = lane & 7;    // 0..7, features 4l..4l+3 within the half

    int beg = row_ptr[node];
    int deg = row_ptr[node + 1] - beg;
    float inv = 1.0f / fmaxf((float)deg, 1.0f);

    float p0 = 0.f, p1 = 0.f, p2 = 0.f, p3 = 0.f;
    float q0 = 0.f, q1 = 0.f, q2 = 0.f, q3 = 0.f;

#pragma unroll
    for (int half = 0; half < 2; ++half) {
        const uint2* __restrict__ Yp = reinterpret_cast<const uint2*>(half ? Yhi : Ylo); // 8/row
        float a0 = 0.f, a1 = 0.f, a2 = 0.f, a3 = 0.f;

        for (int base = 0; base < deg; base += 64) {
            int wend = deg - base; if (wend > 64) wend = 64;
            int mye = base + lane;
            int idxv = (mye < deg) ? (int)csr_src[beg + mye] : 0;
            for (int k = 0; k < wend; k += 32) {
                int e0 = k + g, e1 = k + 8 + g, e2 = k + 16 + g, e3 = k + 24 + g;
                int s0 = __shfl(idxv, e0);
                int s1 = __shfl(idxv, e1);
                int s2 = __shfl(idxv, e2);
                int s3 = __shfl(idxv, e3);
                bool v0 = e0 < wend, v1 = e1 < wend, v2 = e2 < wend, v3 = e3 < wend;
                uint2 r0, r1, r2, r3;
                if (v0) r0 = Yp[s0 * 8 + l];
                if (v1) r1 = Yp[s1 * 8 + l];
                if (v2) r2 = Yp[s2 * 8 + l];
                if (v3) r3 = Yp[s3 * 8 + l];
                if (v0) { a0 += bf16_lo(r0.x); a1 += bf16_hi(r0.x); a2 += bf16_lo(r0.y); a3 += bf16_hi(r0.y); }
                if (v1) { a0 += bf16_lo(r1.x); a1 += bf16_hi(r1.x); a2 += bf16_lo(r1.y); a3 += bf16_hi(r1.y); }
                if (v2) { a0 += bf16_lo(r2.x); a1 += bf16_hi(r2.x); a2 += bf16_lo(r2.y); a3 += bf16_hi(r2.y); }
                if (v3) { a0 += bf16_lo(r3.x); a1 += bf16_hi(r3.x); a2 += bf16_lo(r3.y); a3 += bf16_hi(r3.y); }
            }
        }

        // reduce over the 8 groups
        a0 += __shfl_xor(a0, 8);  a0 += __shfl_xor(a0, 16); a0 += __shfl_xor(a0, 32);
        a1 += __shfl_xor(a1, 8);  a1 += __shfl_xor(a1, 16); a1 += __shfl_xor(a1, 32);
        a2 += __shfl_xor(a2, 8);  a2 += __shfl_xor(a2, 16); a2 += __shfl_xor(a2, 32);
        a3 += __shfl_xor(a3, 8);  a3 += __shfl_xor(a3, 16); a3 += __shfl_xor(a3, 32);

        float4 b = reinterpret_cast<const float4*>(bl)[half * 8 + l];
        uint2 zr = reinterpret_cast<const uint2*>(Zb)[node * 16 + half * 8 + l];
        float v0 = a0 * inv + b.x + bf16_lo(zr.x);
        float v1 = a1 * inv + b.y + bf16_hi(zr.x);
        float v2 = a2 * inv + b.z + bf16_lo(zr.y);
        float v3 = a3 * inv + b.w + bf16_hi(zr.y);
        float o0 = v0 > 0.f ? v0 : expm1f(v0);
        float o1 = v1 > 0.f ? v1 : expm1f(v1);
        float o2 = v2 > 0.f ? v2 : expm1f(v2);
        float o3 = v3 > 0.f ? v3 : expm1f(v3);

        if constexpr (!FUSE_PROJ) {
            if (g == 0) {
                ushort4 ob;
                ob.x = f2bf(o0); ob.y = f2bf(o1); ob.z = f2bf(o2); ob.w = f2bf(o3);
                ushort* Op = half ? Ohi : Olo;
                reinterpret_cast<ushort4*>(Op + (size_t)node * 32)[l] = ob;
            }
        } else {
            float ov[4] = {o0, o1, o2, o3};
#pragma unroll
            for (int j = 0; j < 4; ++j) {
                int k = half * 32 + 4 * l + j;
                float4 wt = reinterpret_cast<const float4*>(Wp)[k];         // Wp[k][0..3]
                float4 wb = reinterpret_cast<const float4*>(Wp)[D_H + k];   // Wp[64+k][0..3]
                p0 += ov[j] * wt.x; p1 += ov[j] * wt.y; p2 += ov[j] * wt.z; p3 += ov[j] * wt.w;
                q0 += ov[j] * wb.x; q1 += ov[j] * wb.y; q2 += ov[j] * wb.z; q3 += ov[j] * wb.w;
            }
        }
    }

    if constexpr (FUSE_PROJ) {
        // reduce over the 8 l-chunks (lanes differing in bits 0..2)
        p0 += __shfl_xor(p0, 1); p0 += __shfl_xor(p0, 2); p0 += __shfl_xor(p0, 4);
        p1 += __shfl_xor(p1, 1); p1 += __shfl_xor(p1, 2); p1 += __shfl_xor(p1, 4);
        p2 += __shfl_xor(p2, 1); p2 += __shfl_xor(p2, 2); p2 += __shfl_xor(p2, 4);
        p3 += __shfl_xor(p3, 1); p3 += __shfl_xor(p3, 2); p3 += __shfl_xor(p3, 4);
        q0 += __shfl_xor(q0, 1); q0 += __shfl_xor(q0, 2); q0 += __shfl_xor(q0, 4);
        q1 += __shfl_xor(q1, 1); q1 += __shfl_xor(q1, 2); q1 += __shfl_xor(q1, 4);
        q2 += __shfl_xor(q2, 1); q2 += __shfl_xor(q2, 2); q2 += __shfl_xor(q2, 4);
        q3 += __shfl_xor(q3, 1); q3 += __shfl_xor(q3, 2); q3 += __shfl_xor(q3, 4);
        if (lane == 0) {
            float4 pv; pv.x = p0; pv.y = p1; pv.z = p2; pv.w = p3;
            float4 qv; qv.x = q0; qv.y = q1; qv.z = q2; qv.w = q3;
            reinterpret_cast<float4*>(ps)[node] = pv;
            reinterpret_cast<float4*>(pd)[node] = qv;
        }
    }
}

__global__ void edge_final_kernel(const int* __restrict__ srcv, const int* __restrict__ dstv,
                                  const float* __restrict__ ps, const float* __restrict__ pd,
                                  const float* __restrict__ bp, float* __restrict__ out) {
    int e = blockIdx.x * 256 + threadIdx.x;
    if (e >= N_EDGES) return;
    float4 a = reinterpret_cast<const float4*>(ps)[srcv[e]];
    float4 b = reinterpret_cast<const float4*>(pd)[dstv[e]];
    float4 o;
    o.x = a.x + b.x + bp[0];
    o.y = a.y + b.y + bp[1];
    o.z = a.z + b.z + bp[2];
    o.w = a.w + b.w + bp[3];
    reinterpret_cast<float4*>(out)[e] = o;
}

extern "C" void kernel_launch(void* const* d_in, const int* in_sizes, int n_in,
                              void* d_out, int out_size, void* d_ws, size_t ws_size,
                              hipStream_t stream) {
    const float* x   = (const float*)d_in[0];
    const int*   ei  = (const int*)d_in[1];
    const float* Wl1 = (const float*)d_in[2];
    const float* bl1 = (const float*)d_in[3];
    const float* Wr1 = (const float*)d_in[4];
    const float* Wl2 = (const float*)d_in[5];
    const float* bl2 = (const float*)d_in[6];
    const float* Wr2 = (const float*)d_in[7];
    const float* Wl3 = (const float*)d_in[8];
    const float* bl3 = (const float*)d_in[9];
    const float* Wr3 = (const float*)d_in[10];
    const float* Wp  = (const float*)d_in[11];
    const float* bp  = (const float*)d_in[12];
    float* out = (float*)d_out;

    const int* srcv = ei;
    const int* dstv = ei + N_EDGES;

    // ---- workspace carve-up ----
    int*   cnt       = (int*)d_ws;                     // 50000
    int*   blockSums = cnt + 50000;                    // 256
    int*   row_ptr   = blockSums + 256;                // 50001
    ushort* rank     = (ushort*)(row_ptr + 50001);     // 800000
    ushort* csr_src  = rank + 800000;                  // 800000
    ushort* wfrag = (ushort*)(((uintptr_t)(csr_src + 800000) + 127) & ~(uintptr_t)127); // 64 KB
    ushort* Ylo = (ushort*)(((uintptr_t)(wfrag + FRAG_TOTAL) + 127) & ~(uintptr_t)127);
    ushort* Yhi  = Ylo + PLANE;
    ushort* Zb   = Yhi + PLANE;            // 64/node interleaved
    ushort* H1lo = Zb + 2 * PLANE;
    ushort* H1hi = H1lo + PLANE;
    ushort* H2lo = H1hi + PLANE;
    ushort* H2hi = H2lo + PLANE;
    float* ps = (float*)(((uintptr_t)(H2hi + PLANE) + 15) & ~(uintptr_t)15);
    float* pd = ps + (size_t)N_NODES * 4;

    // ---- K1: hist+rank || frag build ----
    hipMemsetAsync(cnt, 0, N_NODES * sizeof(int), stream);
    hist_frags_kernel<<<HIST_BLOCKS + 16, 256, 0, stream>>>(dstv, cnt, rank, Wl1, Wr1, Wl2, Wr2,
                                                            Wl3, Wr3, wfrag);
    // ---- K2/K3: scans ----
    scan_partial<<<SCAN_BLOCKS, 256, 0, stream>>>(cnt, blockSums);
    scan_final<<<SCAN_BLOCKS, 256, 0, stream>>>(cnt, blockSums, row_ptr);

    const int GATHER_GRID = (N_NODES + 3) / 4;

    // ---- K4: layer-1 linYZ || rank-based CSR fill ----
    lin1_fill_kernel<<<LIN1_BLOCKS + HIST_BLOCKS, 256, 0, stream>>>(x, wfrag, srcv, dstv,
                                                                    rank, row_ptr, csr_src,
                                                                    Ylo, Yhi, Zb);
    gather_kernel<false><<<GATHER_GRID, 256, 0, stream>>>(Ylo, Yhi, Zb, bl1, row_ptr, csr_src,
                                                          H1lo, H1hi, nullptr, nullptr, nullptr);

    // ---- layer 2 ----
    linYZ_b_kernel<<<LIN1_BLOCKS, 256, 0, stream>>>(H1lo, H1hi, wfrag + F2L, wfrag + F2R,
                                                    Ylo, Yhi, Zb);
    gather_kernel<false><<<GATHER_GRID, 256, 0, stream>>>(Ylo, Yhi, Zb, bl2, row_ptr, csr_src,
                                                          H2lo, H2hi, nullptr, nullptr, nullptr);

    // ---- layer 3, fused output projection ----
    linYZ_b_kernel<<<LIN1_BLOCKS, 256, 0, stream>>>(H2lo, H2hi, wfrag + F3L, wfrag + F3R,
                                                    Ylo, Yhi, Zb);
    gather_kernel<true><<<GATHER_GRID, 256, 0, stream>>>(Ylo, Yhi, Zb, bl3, row_ptr, csr_src,
                                                         nullptr, nullptr, Wp, ps, pd);

    // ---- edge output: out[e] = ps[src] + pd[dst] + bp ----
    edge_final_kernel<<<(N_EDGES + 255) / 256, 256, 0, stream>>>(srcv, dstv, ps, pd, bp, out);
}

// Round 11
// 249.331 us; speedup vs baseline: 1.3241x; 1.3241x over previous
//
#include <hip/hip_runtime.h>
#include <hip/hip_bf16.h>

#define N_NODES 50000
#define N_EDGES 800000
#define D_IN 128
#define D_H 64
#define SCAN_BLOCKS 196   // ceil(50000/256)
#define HIST_BLOCKS 3125  // N_EDGES/256
#define LIN1_BLOCKS 782   // ceil(3125 waves / 4)

// W-fragment table offsets (in ushorts): [kt][nt][lane][8] per matrix
#define F1L 0
#define F1R 8192
#define F2L 16384
#define F2R 20480
#define F3L 24576
#define F3R 28672
#define FRAG_TOTAL 32768  // 64 KB

typedef short bf16x8 __attribute__((ext_vector_type(8)));
typedef float f32x4 __attribute__((ext_vector_type(4)));

__device__ __forceinline__ ushort f2bf(float f) {
    __hip_bfloat16 b = __float2bfloat16(f);
    return *reinterpret_cast<ushort*>(&b);
}
__device__ __forceinline__ float bf16_lo(unsigned int u) { return __uint_as_float(u << 16); }
__device__ __forceinline__ float bf16_hi(unsigned int u) { return __uint_as_float(u & 0xffff0000u); }

// ---------- W-fragment build (device helper) ----------
__device__ __forceinline__ void build_frag_one(const float* __restrict__ W, int local,
                                               ushort* __restrict__ frag, int fid) {
    int lane = local & 63;
    int ktnt = local >> 6;
    int kt = ktnt >> 2, nt = ktnt & 3;
    int quad = lane >> 4, col = lane & 15;
    ushort t0 = f2bf(W[(kt * 32 + quad * 8 + 0) * D_H + nt * 16 + col]);
    ushort t1 = f2bf(W[(kt * 32 + quad * 8 + 1) * D_H + nt * 16 + col]);
    ushort t2 = f2bf(W[(kt * 32 + quad * 8 + 2) * D_H + nt * 16 + col]);
    ushort t3 = f2bf(W[(kt * 32 + quad * 8 + 3) * D_H + nt * 16 + col]);
    ushort t4 = f2bf(W[(kt * 32 + quad * 8 + 4) * D_H + nt * 16 + col]);
    ushort t5 = f2bf(W[(kt * 32 + quad * 8 + 5) * D_H + nt * 16 + col]);
    ushort t6 = f2bf(W[(kt * 32 + quad * 8 + 6) * D_H + nt * 16 + col]);
    ushort t7 = f2bf(W[(kt * 32 + quad * 8 + 7) * D_H + nt * 16 + col]);
    uint4 v;
    v.x = (unsigned int)t0 | ((unsigned int)t1 << 16);
    v.y = (unsigned int)t2 | ((unsigned int)t3 << 16);
    v.z = (unsigned int)t4 | ((unsigned int)t5 << 16);
    v.w = (unsigned int)t6 | ((unsigned int)t7 << 16);
    *reinterpret_cast<uint4*>(frag + (size_t)fid * 8) = v;
}

// ---------- K1: hist+rank (3125 blocks) || build_frags (16 blocks) ----------
__global__ void hist_frags_kernel(const int* __restrict__ dstv, int* __restrict__ cnt,
                                  ushort* __restrict__ rank,
                                  const float* __restrict__ Wl1, const float* __restrict__ Wr1,
                                  const float* __restrict__ Wl2, const float* __restrict__ Wr2,
                                  const float* __restrict__ Wl3, const float* __restrict__ Wr3,
                                  ushort* __restrict__ frag) {
    if (blockIdx.x < HIST_BLOCKS) {
        int e = blockIdx.x * 256 + threadIdx.x;
        if (e < N_EDGES) {
            int r = atomicAdd(&cnt[dstv[e]], 1);
            rank[e] = (ushort)r;
        }
    } else {
        int fid = (blockIdx.x - HIST_BLOCKS) * 256 + threadIdx.x;  // 0..4095
        const float* W; int base;
        if (fid < 1024)      { W = Wl1; base = 0; }
        else if (fid < 2048) { W = Wr1; base = 1024; }
        else if (fid < 2560) { W = Wl2; base = 2048; }
        else if (fid < 3072) { W = Wr2; base = 2560; }
        else if (fid < 3584) { W = Wl3; base = 3072; }
        else                 { W = Wr3; base = 3584; }
        build_frag_one(W, fid - base, frag, fid);
    }
}

// ---------- K2: per-block partial sums ----------
__global__ void scan_partial(const int* __restrict__ cnt, int* __restrict__ blockSums) {
    __shared__ int s[256];
    int i = blockIdx.x * 256 + threadIdx.x;
    s[threadIdx.x] = (i < N_NODES) ? cnt[i] : 0;
    __syncthreads();
    for (int off = 128; off > 0; off >>= 1) {
        if (threadIdx.x < off) s[threadIdx.x] += s[threadIdx.x + off];
        __syncthreads();
    }
    if (threadIdx.x == 0) blockSums[blockIdx.x] = s[0];
}

// ---------- K3: fused blockSums-scan + final scan ----------
__global__ void scan_final(const int* __restrict__ cnt, const int* __restrict__ blockSums,
                           int* __restrict__ row_ptr) {
    __shared__ int s[256];
    __shared__ int bs[256];
    int t = threadIdx.x;
    bs[t] = (t < SCAN_BLOCKS) ? blockSums[t] : 0;
    int i = blockIdx.x * 256 + t;
    s[t] = (i < N_NODES) ? cnt[i] : 0;
    __syncthreads();
    for (int off = 1; off < 256; off <<= 1) {
        int tmp1 = (t >= off) ? s[t - off] : 0;
        int tmp2 = (t >= off) ? bs[t - off] : 0;
        __syncthreads();
        s[t] += tmp1;
        bs[t] += tmp2;
        __syncthreads();
    }
    int blockExcl = (blockIdx.x > 0) ? bs[blockIdx.x - 1] : 0;
    int excl = blockExcl + ((t > 0) ? s[t - 1] : 0);
    if (i < N_NODES) row_ptr[i] = excl;
    if (i == 0) row_ptr[N_NODES] = N_EDGES;
}

// ---------- lin body: Y = bf16(h@Wl), Zb = bf16(h@Wr), one 16-row tile per wave ----------
template <int FIN, bool BF16IN>
__device__ __forceinline__ void lin_body(int gwave, int lane, const void* __restrict__ hin,
                                         const ushort* __restrict__ fragWl,
                                         const ushort* __restrict__ fragWr,
                                         ushort* __restrict__ Y, ushort* __restrict__ Zb) {
    constexpr int KT = FIN / 32;
    int m0 = gwave * 16;
    if (m0 >= N_NODES) return;
    int col = lane & 15;
    int quad = lane >> 4;

    bf16x8 blf[KT][4], brf[KT][4];
#pragma unroll
    for (int kt = 0; kt < KT; ++kt)
#pragma unroll
        for (int nt = 0; nt < 4; ++nt) {
            size_t off = (size_t)((kt * 4 + nt) * 64 + lane) * 8;
            blf[kt][nt] = __builtin_bit_cast(bf16x8, *reinterpret_cast<const uint4*>(fragWl + off));
            brf[kt][nt] = __builtin_bit_cast(bf16x8, *reinterpret_cast<const uint4*>(fragWr + off));
        }

    f32x4 accl0 = {0.f,0.f,0.f,0.f}, accl1 = accl0, accl2 = accl0, accl3 = accl0;
    f32x4 accr0 = accl0, accr1 = accl0, accr2 = accl0, accr3 = accl0;
#pragma unroll
    for (int kt = 0; kt < KT; ++kt) {
        bf16x8 a;
        if (BF16IN) {
            const ushort* arow = (const ushort*)hin + (size_t)(m0 + col) * FIN + quad * 8;
            a = __builtin_bit_cast(bf16x8, *reinterpret_cast<const uint4*>(arow + kt * 32));
        } else {
            const float* arow = (const float*)hin + (size_t)(m0 + col) * FIN + quad * 8;
            float4 a_lo = *reinterpret_cast<const float4*>(arow + kt * 32);
            float4 a_hi = *reinterpret_cast<const float4*>(arow + kt * 32 + 4);
            a[0] = (short)f2bf(a_lo.x); a[1] = (short)f2bf(a_lo.y);
            a[2] = (short)f2bf(a_lo.z); a[3] = (short)f2bf(a_lo.w);
            a[4] = (short)f2bf(a_hi.x); a[5] = (short)f2bf(a_hi.y);
            a[6] = (short)f2bf(a_hi.z); a[7] = (short)f2bf(a_hi.w);
        }
        accl0 = __builtin_amdgcn_mfma_f32_16x16x32_bf16(a, blf[kt][0], accl0, 0, 0, 0);
        accl1 = __builtin_amdgcn_mfma_f32_16x16x32_bf16(a, blf[kt][1], accl1, 0, 0, 0);
        accl2 = __builtin_amdgcn_mfma_f32_16x16x32_bf16(a, blf[kt][2], accl2, 0, 0, 0);
        accl3 = __builtin_amdgcn_mfma_f32_16x16x32_bf16(a, blf[kt][3], accl3, 0, 0, 0);
        accr0 = __builtin_amdgcn_mfma_f32_16x16x32_bf16(a, brf[kt][0], accr0, 0, 0, 0);
        accr1 = __builtin_amdgcn_mfma_f32_16x16x32_bf16(a, brf[kt][1], accr1, 0, 0, 0);
        accr2 = __builtin_amdgcn_mfma_f32_16x16x32_bf16(a, brf[kt][2], accr2, 0, 0, 0);
        accr3 = __builtin_amdgcn_mfma_f32_16x16x32_bf16(a, brf[kt][3], accr3, 0, 0, 0);
    }
#pragma unroll
    for (int reg = 0; reg < 4; ++reg) {
        size_t r = (size_t)(m0 + quad * 4 + reg) * D_H;
        ushort* yp = Y + r;
        yp[0 * 16 + col] = f2bf(accl0[reg]);
        yp[1 * 16 + col] = f2bf(accl1[reg]);
        yp[2 * 16 + col] = f2bf(accl2[reg]);
        yp[3 * 16 + col] = f2bf(accl3[reg]);
        ushort* zp = Zb + r;
        zp[0 * 16 + col] = f2bf(accr0[reg]);
        zp[1 * 16 + col] = f2bf(accr1[reg]);
        zp[2 * 16 + col] = f2bf(accr2[reg]);
        zp[3 * 16 + col] = f2bf(accr3[reg]);
    }
}

// ---------- K4: layer-1 linYZ (fp32 x in, 782 blocks) || rank-based CSR fill ----------
__global__ void lin1_fill_kernel(const float* __restrict__ x, const ushort* __restrict__ wfrag,
                                 const int* __restrict__ srcv, const int* __restrict__ dstv,
                                 const ushort* __restrict__ rank, const int* __restrict__ row_ptr,
                                 ushort* __restrict__ csr_src,
                                 ushort* __restrict__ Y, ushort* __restrict__ Zb) {
    if (blockIdx.x < LIN1_BLOCKS) {
        int gwave = (blockIdx.x * 256 + threadIdx.x) >> 6;
        lin_body<D_IN, false>(gwave, threadIdx.x & 63, x, wfrag + F1L, wfrag + F1R, Y, Zb);
    } else {
        int e = (blockIdx.x - LIN1_BLOCKS) * 256 + threadIdx.x;
        if (e < N_EDGES) {
            int d = dstv[e];
            int pos = row_ptr[d] + (int)rank[e];
            csr_src[pos] = (ushort)srcv[e];
        }
    }
}

// ---------- layers 2/3 linYZ (bf16 in) ----------
__global__ void linYZ_b_kernel(const ushort* __restrict__ hb, const ushort* __restrict__ fragWl,
                               const ushort* __restrict__ fragWr,
                               ushort* __restrict__ Y, ushort* __restrict__ Zb) {
    int gwave = (blockIdx.x * 256 + threadIdx.x) >> 6;
    lin_body<D_H, true>(gwave, threadIdx.x & 63, hb, fragWl, fragWr, Y, Zb);
}

// ---------- per-node gather, TWO nodes per wave (pipelined loads) ----------
// lanes: group g=lane>>4 (0..3) handles edges k+4t+g; l=lane&15 covers features [4l,4l+4).
// 8 unconditional row loads in flight per inner iteration (4 for node A, 4 for node B);
// adds are predicated. csr_src is padded by 64 entries; garbage indices land in Y/Zb (safe).
template <bool FUSE_PROJ>
__global__ void gather_kernel(const ushort* __restrict__ Y, const ushort* __restrict__ Zb,
                              const float* __restrict__ bl,
                              const int* __restrict__ row_ptr, const ushort* __restrict__ csr_src,
                              ushort* __restrict__ outb,
                              const float* __restrict__ Wp,
                              float* __restrict__ ps, float* __restrict__ pd) {
    int wv = (blockIdx.x << 2) + (threadIdx.x >> 6);
    int lane = threadIdx.x & 63;
    int nA = wv << 1;                 // N_NODES = 50000 even: nB always valid
    if (nA >= N_NODES) return;
    int nB = nA + 1;
    int g = lane >> 4;
    int l = lane & 15;

    int rp0 = row_ptr[nA];
    int rp1 = row_ptr[nA + 1];
    int rp2 = row_ptr[nA + 2];
    int degA = rp1 - rp0, degB = rp2 - rp1;

    float a0A=0.f,a1A=0.f,a2A=0.f,a3A=0.f;
    float a0B=0.f,a1B=0.f,a2B=0.f,a3B=0.f;
    const uint2* __restrict__ Y2 = reinterpret_cast<const uint2*>(Y);  // 16 uint2 per row
    int maxdeg = degA > degB ? degA : degB;

    for (int base = 0; base < maxdeg; base += 64) {
        int wendA = degA - base; if (wendA > 64) wendA = 64;
        int wendB = degB - base; if (wendB > 64) wendB = 64;
        int idxA = (int)csr_src[rp0 + base + lane];   // unconditional (padded)
        int idxB = (int)csr_src[rp1 + base + lane];
        int kmax = wendA > wendB ? wendA : wendB;
        for (int k = 0; k < kmax; k += 16) {
            int e0 = k + g, e1 = k + 4 + g, e2 = k + 8 + g, e3 = k + 12 + g;
            int sA0 = __shfl(idxA, e0), sA1 = __shfl(idxA, e1);
            int sA2 = __shfl(idxA, e2), sA3 = __shfl(idxA, e3);
            int sB0 = __shfl(idxB, e0), sB1 = __shfl(idxB, e1);
            int sB2 = __shfl(idxB, e2), sB3 = __shfl(idxB, e3);
            uint2 rA0 = Y2[sA0 * 16 + l], rA1 = Y2[sA1 * 16 + l];
            uint2 rA2 = Y2[sA2 * 16 + l], rA3 = Y2[sA3 * 16 + l];
            uint2 rB0 = Y2[sB0 * 16 + l], rB1 = Y2[sB1 * 16 + l];
            uint2 rB2 = Y2[sB2 * 16 + l], rB3 = Y2[sB3 * 16 + l];
            if (e0 < wendA) { a0A += bf16_lo(rA0.x); a1A += bf16_hi(rA0.x); a2A += bf16_lo(rA0.y); a3A += bf16_hi(rA0.y); }
            if (e1 < wendA) { a0A += bf16_lo(rA1.x); a1A += bf16_hi(rA1.x); a2A += bf16_lo(rA1.y); a3A += bf16_hi(rA1.y); }
            if (e2 < wendA) { a0A += bf16_lo(rA2.x); a1A += bf16_hi(rA2.x); a2A += bf16_lo(rA2.y); a3A += bf16_hi(rA2.y); }
            if (e3 < wendA) { a0A += bf16_lo(rA3.x); a1A += bf16_hi(rA3.x); a2A += bf16_lo(rA3.y); a3A += bf16_hi(rA3.y); }
            if (e0 < wendB) { a0B += bf16_lo(rB0.x); a1B += bf16_hi(rB0.x); a2B += bf16_lo(rB0.y); a3B += bf16_hi(rB0.y); }
            if (e1 < wendB) { a0B += bf16_lo(rB1.x); a1B += bf16_hi(rB1.x); a2B += bf16_lo(rB1.y); a3B += bf16_hi(rB1.y); }
            if (e2 < wendB) { a0B += bf16_lo(rB2.x); a1B += bf16_hi(rB2.x); a2B += bf16_lo(rB2.y); a3B += bf16_hi(rB2.y); }
            if (e3 < wendB) { a0B += bf16_lo(rB3.x); a1B += bf16_hi(rB3.x); a2B += bf16_lo(rB3.y); a3B += bf16_hi(rB3.y); }
        }
    }

    a0A += __shfl_xor(a0A, 16); a0A += __shfl_xor(a0A, 32);
    a1A += __shfl_xor(a1A, 16); a1A += __shfl_xor(a1A, 32);
    a2A += __shfl_xor(a2A, 16); a2A += __shfl_xor(a2A, 32);
    a3A += __shfl_xor(a3A, 16); a3A += __shfl_xor(a3A, 32);
    a0B += __shfl_xor(a0B, 16); a0B += __shfl_xor(a0B, 32);
    a1B += __shfl_xor(a1B, 16); a1B += __shfl_xor(a1B, 32);
    a2B += __shfl_xor(a2B, 16); a2B += __shfl_xor(a2B, 32);
    a3B += __shfl_xor(a3B, 16); a3B += __shfl_xor(a3B, 32);

    if (g < 2) {
        int node  = (g == 0) ? nA : nB;
        float dgf = (float)((g == 0) ? degA : degB);
        float inv = 1.0f / fmaxf(dgf, 1.0f);
        float c0 = (g == 0) ? a0A : a0B;
        float c1 = (g == 0) ? a1A : a1B;
        float c2 = (g == 0) ? a2A : a2B;
        float c3 = (g == 0) ? a3A : a3B;
        float4 bv = reinterpret_cast<const float4*>(bl)[l];
        uint2 zr = reinterpret_cast<const uint2*>(Zb)[node * 16 + l];
        float v0 = c0 * inv + bv.x + bf16_lo(zr.x);
        float v1 = c1 * inv + bv.y + bf16_hi(zr.x);
        float v2 = c2 * inv + bv.z + bf16_lo(zr.y);
        float v3 = c3 * inv + bv.w + bf16_hi(zr.y);
        float o0 = v0 > 0.f ? v0 : expm1f(v0);
        float o1 = v1 > 0.f ? v1 : expm1f(v1);
        float o2 = v2 > 0.f ? v2 : expm1f(v2);
        float o3 = v3 > 0.f ? v3 : expm1f(v3);

        if constexpr (!FUSE_PROJ) {
            ushort4 ob;
            ob.x = f2bf(o0); ob.y = f2bf(o1); ob.z = f2bf(o2); ob.w = f2bf(o3);
            reinterpret_cast<ushort4*>(outb)[node * 16 + l] = ob;
        } else {
            float p0 = 0.f, p1 = 0.f, p2 = 0.f, p3 = 0.f;
            float q0 = 0.f, q1 = 0.f, q2 = 0.f, q3 = 0.f;
            float ov[4] = {o0, o1, o2, o3};
#pragma unroll
            for (int j = 0; j < 4; ++j) {
                int k = 4 * l + j;
                float4 wt = reinterpret_cast<const float4*>(Wp)[k];         // Wp[k][0..3]
                float4 wb = reinterpret_cast<const float4*>(Wp)[D_H + k];   // Wp[64+k][0..3]
                p0 += ov[j] * wt.x; p1 += ov[j] * wt.y; p2 += ov[j] * wt.z; p3 += ov[j] * wt.w;
                q0 += ov[j] * wb.x; q1 += ov[j] * wb.y; q2 += ov[j] * wb.z; q3 += ov[j] * wb.w;
            }
            // reduce within each 16-lane group (bits 0..3)
#pragma unroll
            for (int off = 1; off < 16; off <<= 1) {
                p0 += __shfl_xor(p0, off); p1 += __shfl_xor(p1, off);
                p2 += __shfl_xor(p2, off); p3 += __shfl_xor(p3, off);
                q0 += __shfl_xor(q0, off); q1 += __shfl_xor(q1, off);
                q2 += __shfl_xor(q2, off); q3 += __shfl_xor(q3, off);
            }
            if (l == 0) {
                float4 pv; pv.x = p0; pv.y = p1; pv.z = p2; pv.w = p3;
                float4 qv; qv.x = q0; qv.y = q1; qv.z = q2; qv.w = q3;
                reinterpret_cast<float4*>(ps)[node] = pv;
                reinterpret_cast<float4*>(pd)[node] = qv;
            }
        }
    }
}

__global__ void edge_final_kernel(const int* __restrict__ srcv, const int* __restrict__ dstv,
                                  const float* __restrict__ ps, const float* __restrict__ pd,
                                  const float* __restrict__ bp, float* __restrict__ out) {
    int e = blockIdx.x * 256 + threadIdx.x;
    if (e >= N_EDGES) return;
    float4 a = reinterpret_cast<const float4*>(ps)[srcv[e]];
    float4 b = reinterpret_cast<const float4*>(pd)[dstv[e]];
    float4 o;
    o.x = a.x + b.x + bp[0];
    o.y = a.y + b.y + bp[1];
    o.z = a.z + b.z + bp[2];
    o.w = a.w + b.w + bp[3];
    reinterpret_cast<float4*>(out)[e] = o;
}

extern "C" void kernel_launch(void* const* d_in, const int* in_sizes, int n_in,
                              void* d_out, int out_size, void* d_ws, size_t ws_size,
                              hipStream_t stream) {
    const float* x   = (const float*)d_in[0];
    const int*   ei  = (const int*)d_in[1];
    const float* Wl1 = (const float*)d_in[2];
    const float* bl1 = (const float*)d_in[3];
    const float* Wr1 = (const float*)d_in[4];
    const float* Wl2 = (const float*)d_in[5];
    const float* bl2 = (const float*)d_in[6];
    const float* Wr2 = (const float*)d_in[7];
    const float* Wl3 = (const float*)d_in[8];
    const float* bl3 = (const float*)d_in[9];
    const float* Wr3 = (const float*)d_in[10];
    const float* Wp  = (const float*)d_in[11];
    const float* bp  = (const float*)d_in[12];
    float* out = (float*)d_out;

    const int* srcv = ei;
    const int* dstv = ei + N_EDGES;

    // ---- workspace carve-up ----
    int*   cnt       = (int*)d_ws;                     // 50000
    int*   blockSums = cnt + 50000;                    // 256
    int*   row_ptr   = blockSums + 256;                // 50001
    ushort* rank     = (ushort*)(row_ptr + 50001);     // 800000
    ushort* csr_src  = rank + 800000;                  // 800000 (+64 pad)
    ushort* wfrag = (ushort*)(((uintptr_t)(csr_src + 800064) + 127) & ~(uintptr_t)127); // 64 KB
    ushort* Y   = (ushort*)(((uintptr_t)(wfrag + FRAG_TOTAL) + 127) & ~(uintptr_t)127); // 6.4 MB
    ushort* Zb  = Y + (size_t)N_NODES * D_H;           // 6.4 MB
    ushort* H1b = Zb + (size_t)N_NODES * D_H;          // 6.4 MB
    ushort* H2b = H1b + (size_t)N_NODES * D_H;         // 6.4 MB
    float* ps = (float*)(((uintptr_t)(H2b + (size_t)N_NODES * D_H) + 15) & ~(uintptr_t)15);
    float* pd = ps + (size_t)N_NODES * 4;

    // ---- K1: hist+rank || frag build ----
    hipMemsetAsync(cnt, 0, N_NODES * sizeof(int), stream);
    hist_frags_kernel<<<HIST_BLOCKS + 16, 256, 0, stream>>>(dstv, cnt, rank, Wl1, Wr1, Wl2, Wr2,
                                                            Wl3, Wr3, wfrag);
    // ---- K2/K3: scans ----
    scan_partial<<<SCAN_BLOCKS, 256, 0, stream>>>(cnt, blockSums);
    scan_final<<<SCAN_BLOCKS, 256, 0, stream>>>(cnt, blockSums, row_ptr);

    const int GATHER_GRID = N_NODES / 8;  // 2 nodes/wave, 4 waves/block

    // ---- K4: layer-1 linYZ || rank-based CSR fill ----
    lin1_fill_kernel<<<LIN1_BLOCKS + HIST_BLOCKS, 256, 0, stream>>>(x, wfrag, srcv, dstv,
                                                                    rank, row_ptr, csr_src,
                                                                    Y, Zb);
    gather_kernel<false><<<GATHER_GRID, 256, 0, stream>>>(Y, Zb, bl1, row_ptr, csr_src, H1b,
                                                          nullptr, nullptr, nullptr);

    // ---- layer 2 ----
    linYZ_b_kernel<<<LIN1_BLOCKS, 256, 0, stream>>>(H1b, wfrag + F2L, wfrag + F2R, Y, Zb);
    gather_kernel<false><<<GATHER_GRID, 256, 0, stream>>>(Y, Zb, bl2, row_ptr, csr_src, H2b,
                                                          nullptr, nullptr, nullptr);

    // ---- layer 3, fused output projection (no H store) ----
    linYZ_b_kernel<<<LIN1_BLOCKS, 256, 0, stream>>>(H2b, wfrag + F3L, wfrag + F3R, Y, Zb);
    gather_kernel<true><<<GATHER_GRID, 256, 0, stream>>>(Y, Zb, bl3, row_ptr, csr_src, nullptr,
                                                         Wp, ps, pd);

    // ---- edge output: out[e] = ps[src] + pd[dst] + bp ----
    edge_final_kernel<<<(N_EDGES + 255) / 256, 256, 0, stream>>>(srcv, dstv, ps, pd, bp, out);
}

// Round 12
// 234.609 us; speedup vs baseline: 1.4072x; 1.0628x over previous
//
#include <hip/hip_runtime.h>
#include <hip/hip_bf16.h>

#define N_NODES 50000
#define N_EDGES 800000
#define D_IN 128
#define D_H 64
#define SCAN_BLOCKS 196   // ceil(50000/256)
#define HIST_BLOCKS 3125  // N_EDGES/256
#define LIN1_BLOCKS 782   // ceil(3125 waves / 4)
#define GL_BLOCKS 3125    // 16 nodes/block (4 waves x 4 nodes), 3125*16 = 50000 exactly

// W-fragment table offsets (in ushorts): [kt][nt][lane][8] per matrix
#define F1L 0
#define F1R 8192
#define F2L 16384
#define F2R 20480
#define F3L 24576
#define F3R 28672
#define FRAG_TOTAL 32768  // 64 KB

typedef short bf16x8 __attribute__((ext_vector_type(8)));
typedef float f32x4 __attribute__((ext_vector_type(4)));

__device__ __forceinline__ ushort f2bf(float f) {
    __hip_bfloat16 b = __float2bfloat16(f);
    return *reinterpret_cast<ushort*>(&b);
}
__device__ __forceinline__ float bf16_lo(unsigned int u) { return __uint_as_float(u << 16); }
__device__ __forceinline__ float bf16_hi(unsigned int u) { return __uint_as_float(u & 0xffff0000u); }

// ---------- W-fragment build (device helper) ----------
__device__ __forceinline__ void build_frag_one(const float* __restrict__ W, int local,
                                               ushort* __restrict__ frag, int fid) {
    int lane = local & 63;
    int ktnt = local >> 6;
    int kt = ktnt >> 2, nt = ktnt & 3;
    int quad = lane >> 4, col = lane & 15;
    ushort t0 = f2bf(W[(kt * 32 + quad * 8 + 0) * D_H + nt * 16 + col]);
    ushort t1 = f2bf(W[(kt * 32 + quad * 8 + 1) * D_H + nt * 16 + col]);
    ushort t2 = f2bf(W[(kt * 32 + quad * 8 + 2) * D_H + nt * 16 + col]);
    ushort t3 = f2bf(W[(kt * 32 + quad * 8 + 3) * D_H + nt * 16 + col]);
    ushort t4 = f2bf(W[(kt * 32 + quad * 8 + 4) * D_H + nt * 16 + col]);
    ushort t5 = f2bf(W[(kt * 32 + quad * 8 + 5) * D_H + nt * 16 + col]);
    ushort t6 = f2bf(W[(kt * 32 + quad * 8 + 6) * D_H + nt * 16 + col]);
    ushort t7 = f2bf(W[(kt * 32 + quad * 8 + 7) * D_H + nt * 16 + col]);
    uint4 v;
    v.x = (unsigned int)t0 | ((unsigned int)t1 << 16);
    v.y = (unsigned int)t2 | ((unsigned int)t3 << 16);
    v.z = (unsigned int)t4 | ((unsigned int)t5 << 16);
    v.w = (unsigned int)t6 | ((unsigned int)t7 << 16);
    *reinterpret_cast<uint4*>(frag + (size_t)fid * 8) = v;
}

// ---------- K1: hist+rank (3125 blocks) || build_frags (16 blocks) ----------
__global__ void hist_frags_kernel(const int* __restrict__ dstv, int* __restrict__ cnt,
                                  ushort* __restrict__ rank,
                                  const float* __restrict__ Wl1, const float* __restrict__ Wr1,
                                  const float* __restrict__ Wl2, const float* __restrict__ Wr2,
                                  const float* __restrict__ Wl3, const float* __restrict__ Wr3,
                                  ushort* __restrict__ frag) {
    if (blockIdx.x < HIST_BLOCKS) {
        int e = blockIdx.x * 256 + threadIdx.x;
        if (e < N_EDGES) {
            int r = atomicAdd(&cnt[dstv[e]], 1);
            rank[e] = (ushort)r;
        }
    } else {
        int fid = (blockIdx.x - HIST_BLOCKS) * 256 + threadIdx.x;  // 0..4095
        const float* W; int base;
        if (fid < 1024)      { W = Wl1; base = 0; }
        else if (fid < 2048) { W = Wr1; base = 1024; }
        else if (fid < 2560) { W = Wl2; base = 2048; }
        else if (fid < 3072) { W = Wr2; base = 2560; }
        else if (fid < 3584) { W = Wl3; base = 3072; }
        else                 { W = Wr3; base = 3584; }
        build_frag_one(W, fid - base, frag, fid);
    }
}

// ---------- K2: per-block partial sums ----------
__global__ void scan_partial(const int* __restrict__ cnt, int* __restrict__ blockSums) {
    __shared__ int s[256];
    int i = blockIdx.x * 256 + threadIdx.x;
    s[threadIdx.x] = (i < N_NODES) ? cnt[i] : 0;
    __syncthreads();
    for (int off = 128; off > 0; off >>= 1) {
        if (threadIdx.x < off) s[threadIdx.x] += s[threadIdx.x + off];
        __syncthreads();
    }
    if (threadIdx.x == 0) blockSums[blockIdx.x] = s[0];
}

// ---------- K3: fused blockSums-scan + final scan ----------
__global__ void scan_final(const int* __restrict__ cnt, const int* __restrict__ blockSums,
                           int* __restrict__ row_ptr) {
    __shared__ int s[256];
    __shared__ int bs[256];
    int t = threadIdx.x;
    bs[t] = (t < SCAN_BLOCKS) ? blockSums[t] : 0;
    int i = blockIdx.x * 256 + t;
    s[t] = (i < N_NODES) ? cnt[i] : 0;
    __syncthreads();
    for (int off = 1; off < 256; off <<= 1) {
        int tmp1 = (t >= off) ? s[t - off] : 0;
        int tmp2 = (t >= off) ? bs[t - off] : 0;
        __syncthreads();
        s[t] += tmp1;
        bs[t] += tmp2;
        __syncthreads();
    }
    int blockExcl = (blockIdx.x > 0) ? bs[blockIdx.x - 1] : 0;
    int excl = blockExcl + ((t > 0) ? s[t - 1] : 0);
    if (i < N_NODES) row_ptr[i] = excl;
    if (i == 0) row_ptr[N_NODES] = N_EDGES;
}

// ---------- lin body (layer 1 only): Y = bf16(x@Wl), Zb = bf16(x@Wr) ----------
__device__ __forceinline__ void lin1_body(int gwave, int lane, const float* __restrict__ hin,
                                          const ushort* __restrict__ fragWl,
                                          const ushort* __restrict__ fragWr,
                                          ushort* __restrict__ Y, ushort* __restrict__ Zb) {
    constexpr int KT = D_IN / 32;
    int m0 = gwave * 16;
    if (m0 >= N_NODES) return;
    int col = lane & 15;
    int quad = lane >> 4;

    bf16x8 blf[KT], brf[KT][4];
    bf16x8 blf2[KT][4];
#pragma unroll
    for (int kt = 0; kt < KT; ++kt)
#pragma unroll
        for (int nt = 0; nt < 4; ++nt) {
            size_t off = (size_t)((kt * 4 + nt) * 64 + lane) * 8;
            blf2[kt][nt] = __builtin_bit_cast(bf16x8, *reinterpret_cast<const uint4*>(fragWl + off));
            brf[kt][nt] = __builtin_bit_cast(bf16x8, *reinterpret_cast<const uint4*>(fragWr + off));
        }

    f32x4 accl0 = {0.f,0.f,0.f,0.f}, accl1 = accl0, accl2 = accl0, accl3 = accl0;
    f32x4 accr0 = accl0, accr1 = accl0, accr2 = accl0, accr3 = accl0;
    const float* arow = hin + (size_t)(m0 + col) * D_IN + quad * 8;
#pragma unroll
    for (int kt = 0; kt < KT; ++kt) {
        float4 a_lo = *reinterpret_cast<const float4*>(arow + kt * 32);
        float4 a_hi = *reinterpret_cast<const float4*>(arow + kt * 32 + 4);
        bf16x8 a;
        a[0] = (short)f2bf(a_lo.x); a[1] = (short)f2bf(a_lo.y);
        a[2] = (short)f2bf(a_lo.z); a[3] = (short)f2bf(a_lo.w);
        a[4] = (short)f2bf(a_hi.x); a[5] = (short)f2bf(a_hi.y);
        a[6] = (short)f2bf(a_hi.z); a[7] = (short)f2bf(a_hi.w);
        accl0 = __builtin_amdgcn_mfma_f32_16x16x32_bf16(a, blf2[kt][0], accl0, 0, 0, 0);
        accl1 = __builtin_amdgcn_mfma_f32_16x16x32_bf16(a, blf2[kt][1], accl1, 0, 0, 0);
        accl2 = __builtin_amdgcn_mfma_f32_16x16x32_bf16(a, blf2[kt][2], accl2, 0, 0, 0);
        accl3 = __builtin_amdgcn_mfma_f32_16x16x32_bf16(a, blf2[kt][3], accl3, 0, 0, 0);
        accr0 = __builtin_amdgcn_mfma_f32_16x16x32_bf16(a, brf[kt][0], accr0, 0, 0, 0);
        accr1 = __builtin_amdgcn_mfma_f32_16x16x32_bf16(a, brf[kt][1], accr1, 0, 0, 0);
        accr2 = __builtin_amdgcn_mfma_f32_16x16x32_bf16(a, brf[kt][2], accr2, 0, 0, 0);
        accr3 = __builtin_amdgcn_mfma_f32_16x16x32_bf16(a, brf[kt][3], accr3, 0, 0, 0);
    }
#pragma unroll
    for (int reg = 0; reg < 4; ++reg) {
        size_t r = (size_t)(m0 + quad * 4 + reg) * D_H;
        ushort* yp = Y + r;
        yp[0 * 16 + col] = f2bf(accl0[reg]);
        yp[1 * 16 + col] = f2bf(accl1[reg]);
        yp[2 * 16 + col] = f2bf(accl2[reg]);
        yp[3 * 16 + col] = f2bf(accl3[reg]);
        ushort* zp = Zb + r;
        zp[0 * 16 + col] = f2bf(accr0[reg]);
        zp[1 * 16 + col] = f2bf(accr1[reg]);
        zp[2 * 16 + col] = f2bf(accr2[reg]);
        zp[3 * 16 + col] = f2bf(accr3[reg]);
    }
}

// ---------- K4: layer-1 linYZ (fp32 x in, 782 blocks) || rank-based CSR fill ----------
__global__ void lin1_fill_kernel(const float* __restrict__ x, const ushort* __restrict__ wfrag,
                                 const int* __restrict__ srcv, const int* __restrict__ dstv,
                                 const ushort* __restrict__ rank, const int* __restrict__ row_ptr,
                                 ushort* __restrict__ csr_src,
                                 ushort* __restrict__ Y, ushort* __restrict__ Zb) {
    if (blockIdx.x < LIN1_BLOCKS) {
        int gwave = (blockIdx.x * 256 + threadIdx.x) >> 6;
        lin1_body(gwave, threadIdx.x & 63, x, wfrag + F1L, wfrag + F1R, Y, Zb);
    } else {
        int e = (blockIdx.x - LIN1_BLOCKS) * 256 + threadIdx.x;
        if (e < N_EDGES) {
            int d = dstv[e];
            int pos = row_ptr[d] + (int)rank[e];
            csr_src[pos] = (ushort)srcv[e];
        }
    }
}

// ---------- fused gather(+ELU) then next-layer linYZ through LDS ----------
// block = 16 nodes (4 waves x 4 nodes/wave); gather phase: group g (16 lanes) covers
// feature chunk l of edges k+4j+g; 16 unconditional row loads in flight per iteration.
// FUSE_PROJ=false: epilogue writes o to LDS tile, then each wave computes one 16-col
// n-tile of Ynext/Zbnext via 8 MFMAs. FUSE_PROJ=true: epilogue computes ps/pd instead.
template <bool FUSE_PROJ>
__global__ void gather_lin_kernel(const ushort* __restrict__ Y, const ushort* __restrict__ Zb,
                                  const float* __restrict__ bl,
                                  const int* __restrict__ row_ptr, const ushort* __restrict__ csr_src,
                                  const ushort* __restrict__ fragWl, const ushort* __restrict__ fragWr,
                                  ushort* __restrict__ Ynext, ushort* __restrict__ Zbnext,
                                  const float* __restrict__ Wp,
                                  float* __restrict__ ps, float* __restrict__ pd) {
    __shared__ ushort Hs[16][72];   // 16-row bf16 tile, padded stride (144 B) vs bank conflicts
    int w = threadIdx.x >> 6;       // wave in block
    int lane = threadIdx.x & 63;
    int wv = (blockIdx.x << 2) + w;
    int n0 = wv << 2;               // 4 nodes per wave, 16 per block; 3125*16 = 50000 exact
    int g = lane >> 4;
    int l = lane & 15;

    int rp[5];
#pragma unroll
    for (int i = 0; i < 5; ++i) rp[i] = row_ptr[n0 + i];
    int deg[4];
#pragma unroll
    for (int n = 0; n < 4; ++n) deg[n] = rp[n + 1] - rp[n];
    int maxdeg = deg[0];
#pragma unroll
    for (int n = 1; n < 4; ++n) maxdeg = deg[n] > maxdeg ? deg[n] : maxdeg;

    float acc[4][4] = {{0.f}};
    const uint2* __restrict__ Y2 = reinterpret_cast<const uint2*>(Y);  // 16 uint2 per row

    for (int base = 0; base < maxdeg; base += 64) {
        int idxv[4];
#pragma unroll
        for (int n = 0; n < 4; ++n) idxv[n] = (int)csr_src[rp[n] + base + lane]; // padded
        int wend[4];
#pragma unroll
        for (int n = 0; n < 4; ++n) { wend[n] = deg[n] - base; if (wend[n] > 64) wend[n] = 64; }
        int kmax = wend[0];
#pragma unroll
        for (int n = 1; n < 4; ++n) kmax = wend[n] > kmax ? wend[n] : kmax;
        for (int k = 0; k < kmax; k += 16) {
            uint2 rr[4][4];
#pragma unroll
            for (int n = 0; n < 4; ++n)
#pragma unroll
                for (int j = 0; j < 4; ++j) {
                    int s = __shfl(idxv[n], k + 4 * j + g);
                    rr[n][j] = Y2[s * 16 + l];
                }
#pragma unroll
            for (int n = 0; n < 4; ++n)
#pragma unroll
                for (int j = 0; j < 4; ++j) {
                    if (k + 4 * j + g < wend[n]) {
                        acc[n][0] += bf16_lo(rr[n][j].x); acc[n][1] += bf16_hi(rr[n][j].x);
                        acc[n][2] += bf16_lo(rr[n][j].y); acc[n][3] += bf16_hi(rr[n][j].y);
                    }
                }
        }
    }

#pragma unroll
    for (int n = 0; n < 4; ++n)
#pragma unroll
        for (int f = 0; f < 4; ++f) {
            acc[n][f] += __shfl_xor(acc[n][f], 16);
            acc[n][f] += __shfl_xor(acc[n][f], 32);
        }

    // epilogue: group g owns node n0+g
    int node = n0 + g;
    float dgf = (g == 0) ? (float)deg[0] : (g == 1) ? (float)deg[1]
              : (g == 2) ? (float)deg[2] : (float)deg[3];
    float c0 = (g == 0) ? acc[0][0] : (g == 1) ? acc[1][0] : (g == 2) ? acc[2][0] : acc[3][0];
    float c1 = (g == 0) ? acc[0][1] : (g == 1) ? acc[1][1] : (g == 2) ? acc[2][1] : acc[3][1];
    float c2 = (g == 0) ? acc[0][2] : (g == 1) ? acc[1][2] : (g == 2) ? acc[2][2] : acc[3][2];
    float c3 = (g == 0) ? acc[0][3] : (g == 1) ? acc[1][3] : (g == 2) ? acc[2][3] : acc[3][3];
    float inv = 1.0f / fmaxf(dgf, 1.0f);
    float4 bv = reinterpret_cast<const float4*>(bl)[l];
    uint2 zr = reinterpret_cast<const uint2*>(Zb)[node * 16 + l];
    float v0 = c0 * inv + bv.x + bf16_lo(zr.x);
    float v1 = c1 * inv + bv.y + bf16_hi(zr.x);
    float v2 = c2 * inv + bv.z + bf16_lo(zr.y);
    float v3 = c3 * inv + bv.w + bf16_hi(zr.y);
    float o0 = v0 > 0.f ? v0 : expm1f(v0);
    float o1 = v1 > 0.f ? v1 : expm1f(v1);
    float o2 = v2 > 0.f ? v2 : expm1f(v2);
    float o3 = v3 > 0.f ? v3 : expm1f(v3);

    if constexpr (FUSE_PROJ) {
        float p0 = 0.f, p1 = 0.f, p2 = 0.f, p3 = 0.f;
        float q0 = 0.f, q1 = 0.f, q2 = 0.f, q3 = 0.f;
        float ov[4] = {o0, o1, o2, o3};
#pragma unroll
        for (int j = 0; j < 4; ++j) {
            int k = 4 * l + j;
            float4 wt = reinterpret_cast<const float4*>(Wp)[k];         // Wp[k][0..3]
            float4 wb = reinterpret_cast<const float4*>(Wp)[D_H + k];   // Wp[64+k][0..3]
            p0 += ov[j] * wt.x; p1 += ov[j] * wt.y; p2 += ov[j] * wt.z; p3 += ov[j] * wt.w;
            q0 += ov[j] * wb.x; q1 += ov[j] * wb.y; q2 += ov[j] * wb.z; q3 += ov[j] * wb.w;
        }
#pragma unroll
        for (int off = 1; off < 16; off <<= 1) {
            p0 += __shfl_xor(p0, off); p1 += __shfl_xor(p1, off);
            p2 += __shfl_xor(p2, off); p3 += __shfl_xor(p3, off);
            q0 += __shfl_xor(q0, off); q1 += __shfl_xor(q1, off);
            q2 += __shfl_xor(q2, off); q3 += __shfl_xor(q3, off);
        }
        if (l == 0) {
            float4 pv; pv.x = p0; pv.y = p1; pv.z = p2; pv.w = p3;
            float4 qv; qv.x = q0; qv.y = q1; qv.z = q2; qv.w = q3;
            reinterpret_cast<float4*>(ps)[node] = pv;
            reinterpret_cast<float4*>(pd)[node] = qv;
        }
    } else {
        // stash o in the LDS tile, then next-layer lin on the 16-node tile
        ushort4 ob;
        ob.x = f2bf(o0); ob.y = f2bf(o1); ob.z = f2bf(o2); ob.w = f2bf(o3);
        int localrow = w * 4 + g;
        *reinterpret_cast<ushort4*>(&Hs[localrow][4 * l]) = ob;
        __syncthreads();

        int col = lane & 15;
        int quad = lane >> 4;
        // B-frags: wave w = n-tile w
        bf16x8 blf0 = __builtin_bit_cast(bf16x8,
            *reinterpret_cast<const uint4*>(fragWl + (size_t)((0 * 4 + w) * 64 + lane) * 8));
        bf16x8 blf1 = __builtin_bit_cast(bf16x8,
            *reinterpret_cast<const uint4*>(fragWl + (size_t)((1 * 4 + w) * 64 + lane) * 8));
        bf16x8 brf0 = __builtin_bit_cast(bf16x8,
            *reinterpret_cast<const uint4*>(fragWr + (size_t)((0 * 4 + w) * 64 + lane) * 8));
        bf16x8 brf1 = __builtin_bit_cast(bf16x8,
            *reinterpret_cast<const uint4*>(fragWr + (size_t)((1 * 4 + w) * 64 + lane) * 8));
        // A-frags from LDS
        bf16x8 a0 = __builtin_bit_cast(bf16x8,
            *reinterpret_cast<const uint4*>(&Hs[col][quad * 8]));
        bf16x8 a1 = __builtin_bit_cast(bf16x8,
            *reinterpret_cast<const uint4*>(&Hs[col][32 + quad * 8]));
        f32x4 accl = {0.f,0.f,0.f,0.f};
        f32x4 accr = {0.f,0.f,0.f,0.f};
        accl = __builtin_amdgcn_mfma_f32_16x16x32_bf16(a0, blf0, accl, 0, 0, 0);
        accl = __builtin_amdgcn_mfma_f32_16x16x32_bf16(a1, blf1, accl, 0, 0, 0);
        accr = __builtin_amdgcn_mfma_f32_16x16x32_bf16(a0, brf0, accr, 0, 0, 0);
        accr = __builtin_amdgcn_mfma_f32_16x16x32_bf16(a1, brf1, accr, 0, 0, 0);

        int n0base = blockIdx.x * 16;
#pragma unroll
        for (int reg = 0; reg < 4; ++reg) {
            size_t r = (size_t)(n0base + quad * 4 + reg) * D_H + w * 16 + col;
            Ynext[r]  = f2bf(accl[reg]);
            Zbnext[r] = f2bf(accr[reg]);
        }
    }
}

__global__ void edge_final_kernel(const int* __restrict__ srcv, const int* __restrict__ dstv,
                                  const float* __restrict__ ps, const float* __restrict__ pd,
                                  const float* __restrict__ bp, float* __restrict__ out) {
    int e = blockIdx.x * 256 + threadIdx.x;
    if (e >= N_EDGES) return;
    float4 a = reinterpret_cast<const float4*>(ps)[srcv[e]];
    float4 b = reinterpret_cast<const float4*>(pd)[dstv[e]];
    float4 o;
    o.x = a.x + b.x + bp[0];
    o.y = a.y + b.y + bp[1];
    o.z = a.z + b.z + bp[2];
    o.w = a.w + b.w + bp[3];
    reinterpret_cast<float4*>(out)[e] = o;
}

extern "C" void kernel_launch(void* const* d_in, const int* in_sizes, int n_in,
                              void* d_out, int out_size, void* d_ws, size_t ws_size,
                              hipStream_t stream) {
    const float* x   = (const float*)d_in[0];
    const int*   ei  = (const int*)d_in[1];
    const float* Wl1 = (const float*)d_in[2];
    const float* bl1 = (const float*)d_in[3];
    const float* Wr1 = (const float*)d_in[4];
    const float* Wl2 = (const float*)d_in[5];
    const float* bl2 = (const float*)d_in[6];
    const float* Wr2 = (const float*)d_in[7];
    const float* Wl3 = (const float*)d_in[8];
    const float* bl3 = (const float*)d_in[9];
    const float* Wr3 = (const float*)d_in[10];
    const float* Wp  = (const float*)d_in[11];
    const float* bp  = (const float*)d_in[12];
    float* out = (float*)d_out;

    const int* srcv = ei;
    const int* dstv = ei + N_EDGES;

    // ---- workspace carve-up ----
    int*   cnt       = (int*)d_ws;                     // 50000
    int*   blockSums = cnt + 50000;                    // 256
    int*   row_ptr   = blockSums + 256;                // 50001
    ushort* rank     = (ushort*)(row_ptr + 50001);     // 800000
    ushort* csr_src  = rank + 800000;                  // 800000 (+4096 pad)
    ushort* wfrag = (ushort*)(((uintptr_t)(csr_src + 800000 + 4096) + 127) & ~(uintptr_t)127);
    ushort* Y1  = (ushort*)(((uintptr_t)(wfrag + FRAG_TOTAL) + 127) & ~(uintptr_t)127); // 6.4 MB
    ushort* Zb1 = Y1 + (size_t)N_NODES * D_H;          // 6.4 MB
    ushort* Y2  = Zb1 + (size_t)N_NODES * D_H;         // 6.4 MB
    ushort* Zb2 = Y2 + (size_t)N_NODES * D_H;          // 6.4 MB
    float* ps = (float*)(((uintptr_t)(Zb2 + (size_t)N_NODES * D_H) + 15) & ~(uintptr_t)15);
    float* pd = ps + (size_t)N_NODES * 4;

    // ---- K1: hist+rank || frag build ----
    hipMemsetAsync(cnt, 0, N_NODES * sizeof(int), stream);
    hist_frags_kernel<<<HIST_BLOCKS + 16, 256, 0, stream>>>(dstv, cnt, rank, Wl1, Wr1, Wl2, Wr2,
                                                            Wl3, Wr3, wfrag);
    // ---- K2/K3: scans ----
    scan_partial<<<SCAN_BLOCKS, 256, 0, stream>>>(cnt, blockSums);
    scan_final<<<SCAN_BLOCKS, 256, 0, stream>>>(cnt, blockSums, row_ptr);

    // ---- K4: layer-1 linYZ || rank-based CSR fill ----
    lin1_fill_kernel<<<LIN1_BLOCKS + HIST_BLOCKS, 256, 0, stream>>>(x, wfrag, srcv, dstv,
                                                                    rank, row_ptr, csr_src,
                                                                    Y1, Zb1);

    // ---- K5: gather L1 + lin L2 (fused) : Y1/Zb1 -> Y2/Zb2 ----
    gather_lin_kernel<false><<<GL_BLOCKS, 256, 0, stream>>>(Y1, Zb1, bl1, row_ptr, csr_src,
                                                            wfrag + F2L, wfrag + F2R, Y2, Zb2,
                                                            nullptr, nullptr, nullptr);

    // ---- K6: gather L2 + lin L3 (fused) : Y2/Zb2 -> Y1/Zb1 ----
    gather_lin_kernel<false><<<GL_BLOCKS, 256, 0, stream>>>(Y2, Zb2, bl2, row_ptr, csr_src,
                                                            wfrag + F3L, wfrag + F3R, Y1, Zb1,
                                                            nullptr, nullptr, nullptr);

    // ---- K7: gather L3 + fused output projection ----
    gather_lin_kernel<true><<<GL_BLOCKS, 256, 0, stream>>>(Y1, Zb1, bl3, row_ptr, csr_src,
                                                           nullptr, nullptr, nullptr, nullptr,
                                                           Wp, ps, pd);

    // ---- K8: edge output: out[e] = ps[src] + pd[dst] + bp ----
    edge_final_kernel<<<(N_EDGES + 255) / 256, 256, 0, stream>>>(srcv, dstv, ps, pd, bp, out);
}